// Round 9
// baseline (34.019 us; speedup 1.0000x reference)
//
#include <hip/hip_runtime.h>

#define E  9
#define B_ 8
#define H_ 224
#define W_ 224
#define C_ 32
#define TH 4                        // 224/4=56 strips -> 3136 blocks = 12.25/CU
#define WT 32                       // w pixels per block
#define STRIPS (H_ / TH)            // 56
#define WTILES (W_ / WT)            // 7
#define NBLK (B_ * STRIPS * WTILES) // 3136 (divisible by 8 -> clean XCD swizzle)

typedef float    v2f __attribute__((ext_vector_type(2)));
typedef float    v4f __attribute__((ext_vector_type(4)));   // clang-native: ok for nontemporal builtin
typedef unsigned uv2 __attribute__((ext_vector_type(2)));

__device__ __forceinline__ v2f vabs2(v2f x) {
    uv2 u = __builtin_bit_cast(uv2, x);
    u &= 0x7fffffffu;
    return __builtin_bit_cast(v2f, u);
}

__global__ __launch_bounds__(256) void fm_main(const float* __restrict__ inp,
                                               const float* __restrict__ kern,
                                               const float* __restrict__ mask,
                                               float* __restrict__ out) {
    __shared__ float s_m[E * C_];
    __shared__ float s_nk[E * C_];   // NEGATED kernel -> diff is one packed fma
    __shared__ float s_red[4];

    // ---- Folded prep: every block computes global max(|mask|) over 288 elems.
    int t = threadIdx.x;
    {
        float a0 = (t < E * C_) ? fabsf(mask[t]) : 0.0f;
        float a1 = (t < E * C_ - 256) ? fabsf(mask[t + 256]) : 0.0f;
        float mx = fmaxf(a0, a1);
#pragma unroll
        for (int off = 32; off >= 1; off >>= 1)
            mx = fmaxf(mx, __shfl_xor(mx, off));
        if ((t & 63) == 0) s_red[t >> 6] = mx;
        __syncthreads();
        float gmx = fmaxf(fmaxf(s_red[0], s_red[1]), fmaxf(s_red[2], s_red[3]));
        float inv = 1.0f / (gmx + 1e-6f);
        if (t < E * C_) {
            s_m[t]  = fabsf(mask[t]) * inv;
            s_nk[t] = -kern[t];
            if (t < E * C_ - 256) {
                s_m[t + 256]  = fabsf(mask[t + 256]) * inv;
                s_nk[t + 256] = -kern[t + 256];
            }
        }
        __syncthreads();
    }

    // Bijective XCD-chunk swizzle: each XCD gets a contiguous chunk (392 blocks).
    int bid = blockIdx.x;
    int swz = (bid & 7) * (NBLK / 8) + (bid >> 3);
    int bw  = swz % WTILES;
    int t2  = swz / WTILES;
    int hs  = (t2 % STRIPS) * TH;   // strip start row
    int b   = t2 / STRIPS;

    int cq = (t & 7) << 2;          // channel quad: 0,4,...,28
    int wl = t >> 3;                // 0..31
    int w  = bw * WT + wl;

    const float* base = inp + (((size_t)b * H_ * W_ + w) * C_) + cq;
    bool wm = (w > 0);
    bool wp = (w < W_ - 1);

    const float4 z4 = make_float4(0.f, 0.f, 0.f, 0.f);

    float4 win[3][3];   // [ring slot][x-offset -1,0,+1]

    auto ld3 = [&](int hh, float4* r) {
        if ((unsigned)hh < (unsigned)H_) {   // block-uniform branch
            const float* p = base + (size_t)hh * (W_ * C_);
            r[0] = wm ? *reinterpret_cast<const float4*>(p - C_) : z4;
            r[1] = *reinterpret_cast<const float4*>(p);
            r[2] = wp ? *reinterpret_cast<const float4*>(p + C_) : z4;
        } else {
            r[0] = z4; r[1] = z4; r[2] = z4;
        }
    };

    ld3(hs - 1, win[0]);
    ld3(hs,     win[1]);

    const float inv9 = 1.0f / 9.0f;
    const v2f inv9v = {inv9, inv9};
    const v2f onev  = {1.0f, 1.0f};

#pragma unroll
    for (int s = 0; s < TH; ++s) {
        ld3(hs + s + 1, win[(s + 2) % 3]);

        const float4* rm1 = win[(s + 0) % 3];   // row h-1
        const float4* r0  = win[(s + 1) % 3];   // row h
        const float4* rp1 = win[(s + 2) % 3];   // row h+1

        // tap order: e=0 center, then (y,x) raster skipping center
        float4 taps[E];
        taps[0] = r0[1];
        taps[1] = rm1[0]; taps[2] = rm1[1]; taps[3] = rm1[2];
        taps[4] = r0[0];  taps[5] = r0[2];
        taps[6] = rp1[0]; taps[7] = rp1[1]; taps[8] = rp1[2];

        v2f alo[E], ahi[E];
        v2f nlo = {0.f, 0.f}, nhi = {0.f, 0.f};
        v2f slo = {0.f, 0.f}, shi = {0.f, 0.f};

#pragma unroll
        for (int e = 0; e < E; ++e) {
            const v2f* tp = reinterpret_cast<const v2f*>(&taps[e]);
            const v2f* mp = reinterpret_cast<const v2f*>(s_m  + e * C_ + cq);
            const v2f* kp = reinterpret_cast<const v2f*>(s_nk + e * C_ + cq);
            v2f dlo = tp[0] * mp[0] + kp[0];    // v_pk_fma_f32
            v2f dhi = tp[1] * mp[1] + kp[1];
            v2f al = vabs2(dlo), ah = vabs2(dhi);
            alo[e] = al; ahi[e] = ah;
            nlo += al; nhi += ah;               // v_pk_add_f32
            slo += dlo; shi += dhi;
        }

        v2f mlo = slo * inv9v, mhi = shi * inv9v;

        v2f vlo = {0.f, 0.f}, vhi = {0.f, 0.f};
#pragma unroll
        for (int e = 0; e < E; ++e) {
            vlo += vabs2(alo[e] - mlo);
            vhi += vabs2(ahi[e] - mhi);
        }

        v2f olo = (onev - vlo * inv9v) * (onev - nlo * inv9v);
        v2f ohi = (onev - vhi * inv9v) * (onev - nhi * inv9v);

        v4f o;
        o.x = olo.x; o.y = olo.y; o.z = ohi.x; o.w = ohi.y;

        // Output is write-once/never-read: non-temporal keeps it out of L2/L3.
        float* op = out + (((size_t)b * H_ + (hs + s)) * W_ + w) * C_ + cq;
        __builtin_nontemporal_store(o, reinterpret_cast<v4f*>(op));
    }
}

extern "C" void kernel_launch(void* const* d_in, const int* in_sizes, int n_in,
                              void* d_out, int out_size, void* d_ws, size_t ws_size,
                              hipStream_t stream) {
    const float* inp  = (const float*)d_in[0];
    const float* kern = (const float*)d_in[1];
    const float* mask = (const float*)d_in[2];
    float* out = (float*)d_out;

    fm_main<<<NBLK, 256, 0, stream>>>(inp, kern, mask, out);
}

// Round 10
// 30.184 us; speedup vs baseline: 1.1271x; 1.1271x over previous
//
#include <hip/hip_runtime.h>

#define E  9
#define B_ 8
#define H_ 224
#define W_ 224
#define C_ 32
#define TH 7                        // 224/7=32 strips -> 1792 blocks = exactly 7/CU
#define WT 32                       // w pixels per block
#define STRIPS (H_ / TH)            // 32
#define WTILES (W_ / WT)            // 7
#define NBLK (B_ * STRIPS * WTILES) // 1792 (one batch image per XCD after swizzle)

typedef float v4f __attribute__((ext_vector_type(4)));

__global__ __launch_bounds__(256, 3) void fm_main(const float* __restrict__ inp,
                                                  const float* __restrict__ kern,
                                                  const float* __restrict__ mask,
                                                  float* __restrict__ out) {
    __shared__ float s_m[E * C_];
    __shared__ float s_nk[E * C_];   // NEGATED kernel -> diff is one fma
    __shared__ float s_red[4];

    // ---- Folded prep: every block computes global max(|mask|) over 288 elems.
    int t = threadIdx.x;
    {
        float a0 = (t < E * C_) ? fabsf(mask[t]) : 0.0f;
        float a1 = (t < E * C_ - 256) ? fabsf(mask[t + 256]) : 0.0f;
        float mx = fmaxf(a0, a1);
#pragma unroll
        for (int off = 32; off >= 1; off >>= 1)
            mx = fmaxf(mx, __shfl_xor(mx, off));
        if ((t & 63) == 0) s_red[t >> 6] = mx;
        __syncthreads();
        float gmx = fmaxf(fmaxf(s_red[0], s_red[1]), fmaxf(s_red[2], s_red[3]));
        float inv = 1.0f / (gmx + 1e-6f);
        if (t < E * C_) {
            s_m[t]  = fabsf(mask[t]) * inv;
            s_nk[t] = -kern[t];
            if (t < E * C_ - 256) {
                s_m[t + 256]  = fabsf(mask[t + 256]) * inv;
                s_nk[t + 256] = -kern[t + 256];
            }
        }
        __syncthreads();
    }

    // Bijective XCD-chunk swizzle: each XCD gets one batch image (224 blocks).
    int bid = blockIdx.x;
    int swz = (bid & 7) * (NBLK / 8) + (bid >> 3);
    int bw  = swz % WTILES;
    int t2  = swz / WTILES;
    int hs  = (t2 % STRIPS) * TH;   // strip start row
    int b   = t2 / STRIPS;

    int cq = (t & 7) << 2;          // channel quad: 0,4,...,28
    int wl = t >> 3;                // 0..31
    int w  = bw * WT + wl;

    // Coefficients: LDS -> registers ONCE per thread (was 18 KB of LDS return
    // bandwidth per wave-ROW; now once per wave). asm pin defeats the
    // scheduler's sink-into-loop heuristic (R4's failure mode).
    v4f cm[E], ck[E];
#pragma unroll
    for (int e = 0; e < E; ++e) {
        cm[e] = *reinterpret_cast<const v4f*>(s_m  + e * C_ + cq);
        ck[e] = *reinterpret_cast<const v4f*>(s_nk + e * C_ + cq);
    }
#pragma unroll
    for (int e = 0; e < E; ++e)
        asm volatile("" :: "v"(cm[e]), "v"(ck[e]));

    const float* base = inp + (((size_t)b * H_ * W_ + w) * C_) + cq;
    bool wm = (w > 0);
    bool wp = (w < W_ - 1);

    const v4f z4 = {0.f, 0.f, 0.f, 0.f};

    v4f win[3][3];   // [ring slot][x-offset -1,0,+1]

    auto ld3 = [&](int hh, v4f* r) {
        if ((unsigned)hh < (unsigned)H_) {   // block-uniform branch
            const float* p = base + (size_t)hh * (W_ * C_);
            r[0] = wm ? *reinterpret_cast<const v4f*>(p - C_) : z4;
            r[1] = *reinterpret_cast<const v4f*>(p);
            r[2] = wp ? *reinterpret_cast<const v4f*>(p + C_) : z4;
        } else {
            r[0] = z4; r[1] = z4; r[2] = z4;
        }
    };

    ld3(hs - 1, win[0]);
    ld3(hs,     win[1]);

    const float inv9 = 1.0f / 9.0f;

#pragma unroll
    for (int s = 0; s < TH; ++s) {
        ld3(hs + s + 1, win[(s + 2) % 3]);

        const v4f* rm1 = win[(s + 0) % 3];   // row h-1
        const v4f* r0  = win[(s + 1) % 3];   // row h
        const v4f* rp1 = win[(s + 2) % 3];   // row h+1

        // tap order: e=0 center, then (y,x) raster skipping center
        v4f taps[E];
        taps[0] = r0[1];
        taps[1] = rm1[0]; taps[2] = rm1[1]; taps[3] = rm1[2];
        taps[4] = r0[0];  taps[5] = r0[2];
        taps[6] = rp1[0]; taps[7] = rp1[1]; taps[8] = rp1[2];

        v4f o;

        // ---- channels x,y ----  (store d, keep every abs as a src modifier)
        {
            float dA[E], dB[E];
            float n0 = 0.f, n1 = 0.f, sm0 = 0.f, sm1 = 0.f;
#pragma unroll
            for (int e = 0; e < E; ++e) {
                float d0 = fmaf(taps[e].x, cm[e].x, ck[e].x);
                float d1 = fmaf(taps[e].y, cm[e].y, ck[e].y);
                dA[e] = d0; dB[e] = d1;
                n0 += fabsf(d0); n1 += fabsf(d1);
                sm0 += d0; sm1 += d1;
            }
            float nm0 = sm0 * (-inv9), nm1 = sm1 * (-inv9);
            float v0 = 0.f, v1 = 0.f;
#pragma unroll
            for (int e = 0; e < E; ++e) {
                v0 += fabsf(fabsf(dA[e]) + nm0);
                v1 += fabsf(fabsf(dB[e]) + nm1);
            }
            o.x = fmaf(v0, -inv9, 1.0f) * fmaf(n0, -inv9, 1.0f);
            o.y = fmaf(v1, -inv9, 1.0f) * fmaf(n1, -inv9, 1.0f);
        }
        // ---- channels z,w ----
        {
            float dA[E], dB[E];
            float n0 = 0.f, n1 = 0.f, sm0 = 0.f, sm1 = 0.f;
#pragma unroll
            for (int e = 0; e < E; ++e) {
                float d0 = fmaf(taps[e].z, cm[e].z, ck[e].z);
                float d1 = fmaf(taps[e].w, cm[e].w, ck[e].w);
                dA[e] = d0; dB[e] = d1;
                n0 += fabsf(d0); n1 += fabsf(d1);
                sm0 += d0; sm1 += d1;
            }
            float nm0 = sm0 * (-inv9), nm1 = sm1 * (-inv9);
            float v0 = 0.f, v1 = 0.f;
#pragma unroll
            for (int e = 0; e < E; ++e) {
                v0 += fabsf(fabsf(dA[e]) + nm0);
                v1 += fabsf(fabsf(dB[e]) + nm1);
            }
            o.z = fmaf(v0, -inv9, 1.0f) * fmaf(n0, -inv9, 1.0f);
            o.w = fmaf(v1, -inv9, 1.0f) * fmaf(n1, -inv9, 1.0f);
        }

        // Output is write-once/never-read: non-temporal keeps it out of L2/L3.
        float* op = out + (((size_t)b * H_ + (hs + s)) * W_ + w) * C_ + cq;
        __builtin_nontemporal_store(o, reinterpret_cast<v4f*>(op));
    }
}

extern "C" void kernel_launch(void* const* d_in, const int* in_sizes, int n_in,
                              void* d_out, int out_size, void* d_ws, size_t ws_size,
                              hipStream_t stream) {
    const float* inp  = (const float*)d_in[0];
    const float* kern = (const float*)d_in[1];
    const float* mask = (const float*)d_in[2];
    float* out = (float*)d_out;

    fm_main<<<NBLK, 256, 0, stream>>>(inp, kern, mask, out);
}

// Round 11
// 29.734 us; speedup vs baseline: 1.1441x; 1.0151x over previous
//
#include <hip/hip_runtime.h>

#define E  9
#define B_ 8
#define H_ 224
#define W_ 224
#define C_ 32
#define TH 7                        // 224/7=32 strips -> 1792 blocks = exactly 7/CU
#define WT 32                       // w pixels per block
#define STRIPS (H_ / TH)            // 32
#define WTILES (W_ / WT)            // 7
#define NBLK (B_ * STRIPS * WTILES) // 1792 (one batch image per XCD after swizzle)

typedef float v4f __attribute__((ext_vector_type(4)));

__global__ __launch_bounds__(256, 3) void fm_main(const float* __restrict__ inp,
                                                  const float* __restrict__ kern,
                                                  const float* __restrict__ mask,
                                                  float* __restrict__ out) {
    int t = threadIdx.x;

    // Bijective XCD-chunk swizzle: each XCD gets one batch image (224 blocks).
    int bid = blockIdx.x;
    int swz = (bid & 7) * (NBLK / 8) + (bid >> 3);
    int bw  = swz % WTILES;
    int t2  = swz / WTILES;
    int hs  = (t2 % STRIPS) * TH;   // strip start row
    int b   = t2 / STRIPS;

    int cq = (t & 7) << 2;          // channel quad: 0,4,...,28
    int wl = t >> 3;                // 0..31
    int w  = bw * WT + wl;

    // ---- Barrier-free, LDS-free prep -------------------------------------
    // Each thread loads its (E x 4ch) slice of mask+kern straight from global
    // (L1-broadcast). Lanes 0..7 of each 8-lane group jointly cover all 32
    // channels, so shfl_xor over offsets 1,2,4 yields the GLOBAL max(|mask|)
    // in every lane: no __syncthreads, no LDS, no serial prep phase.
    v4f cm[E], ck[E];
    float mx = 0.0f;
#pragma unroll
    for (int e = 0; e < E; ++e) {
        v4f mv = *reinterpret_cast<const v4f*>(mask + e * C_ + cq);
        v4f kv = *reinterpret_cast<const v4f*>(kern + e * C_ + cq);
        mx = fmaxf(mx, fmaxf(fmaxf(fabsf(mv.x), fabsf(mv.y)),
                             fmaxf(fabsf(mv.z), fabsf(mv.w))));
        cm[e] = mv; ck[e] = kv;
    }
    mx = fmaxf(mx, __shfl_xor(mx, 1));
    mx = fmaxf(mx, __shfl_xor(mx, 2));
    mx = fmaxf(mx, __shfl_xor(mx, 4));
    float inv = 1.0f / (mx + 1e-6f);
#pragma unroll
    for (int e = 0; e < E; ++e) {
        cm[e].x = fabsf(cm[e].x) * inv;   // abs folds as src modifier on v_mul
        cm[e].y = fabsf(cm[e].y) * inv;
        cm[e].z = fabsf(cm[e].z) * inv;
        cm[e].w = fabsf(cm[e].w) * inv;
    }
#pragma unroll
    for (int e = 0; e < E; ++e)
        asm volatile("" :: "v"(cm[e]), "v"(ck[e]));   // pin: no sink-into-loop

    const float* base = inp + (((size_t)b * H_ * W_ + w) * C_) + cq;
    bool wm = (w > 0);
    bool wp = (w < W_ - 1);

    const v4f z4 = {0.f, 0.f, 0.f, 0.f};

    v4f win[3][3];   // [ring slot][x-offset -1,0,+1]

    auto ld3 = [&](int hh, v4f* r) {
        if ((unsigned)hh < (unsigned)H_) {   // block-uniform branch
            const float* p = base + (size_t)hh * (W_ * C_);
            r[0] = wm ? *reinterpret_cast<const v4f*>(p - C_) : z4;
            r[1] = *reinterpret_cast<const v4f*>(p);
            r[2] = wp ? *reinterpret_cast<const v4f*>(p + C_) : z4;
        } else {
            r[0] = z4; r[1] = z4; r[2] = z4;
        }
    };

    ld3(hs - 1, win[0]);
    ld3(hs,     win[1]);

    const float inv9 = 1.0f / 9.0f;

#pragma unroll
    for (int s = 0; s < TH; ++s) {
        ld3(hs + s + 1, win[(s + 2) % 3]);

        const v4f* rm1 = win[(s + 0) % 3];   // row h-1
        const v4f* r0  = win[(s + 1) % 3];   // row h
        const v4f* rp1 = win[(s + 2) % 3];   // row h+1

        // tap order: e=0 center, then (y,x) raster skipping center
        v4f taps[E];
        taps[0] = r0[1];
        taps[1] = rm1[0]; taps[2] = rm1[1]; taps[3] = rm1[2];
        taps[4] = r0[0];  taps[5] = r0[2];
        taps[6] = rp1[0]; taps[7] = rp1[1]; taps[8] = rp1[2];

        v4f o;

        // ---- channels x,y ----  (d = tap*m - k; neg on k folds into fma)
        {
            float dA[E], dB[E];
            float n0 = 0.f, n1 = 0.f, sm0 = 0.f, sm1 = 0.f;
#pragma unroll
            for (int e = 0; e < E; ++e) {
                float d0 = fmaf(taps[e].x, cm[e].x, -ck[e].x);
                float d1 = fmaf(taps[e].y, cm[e].y, -ck[e].y);
                dA[e] = d0; dB[e] = d1;
                n0 += fabsf(d0); n1 += fabsf(d1);
                sm0 += d0; sm1 += d1;
            }
            float nm0 = sm0 * (-inv9), nm1 = sm1 * (-inv9);
            float v0 = 0.f, v1 = 0.f;
#pragma unroll
            for (int e = 0; e < E; ++e) {
                v0 += fabsf(fabsf(dA[e]) + nm0);
                v1 += fabsf(fabsf(dB[e]) + nm1);
            }
            o.x = fmaf(v0, -inv9, 1.0f) * fmaf(n0, -inv9, 1.0f);
            o.y = fmaf(v1, -inv9, 1.0f) * fmaf(n1, -inv9, 1.0f);
        }
        // ---- channels z,w ----
        {
            float dA[E], dB[E];
            float n0 = 0.f, n1 = 0.f, sm0 = 0.f, sm1 = 0.f;
#pragma unroll
            for (int e = 0; e < E; ++e) {
                float d0 = fmaf(taps[e].z, cm[e].z, -ck[e].z);
                float d1 = fmaf(taps[e].w, cm[e].w, -ck[e].w);
                dA[e] = d0; dB[e] = d1;
                n0 += fabsf(d0); n1 += fabsf(d1);
                sm0 += d0; sm1 += d1;
            }
            float nm0 = sm0 * (-inv9), nm1 = sm1 * (-inv9);
            float v0 = 0.f, v1 = 0.f;
#pragma unroll
            for (int e = 0; e < E; ++e) {
                v0 += fabsf(fabsf(dA[e]) + nm0);
                v1 += fabsf(fabsf(dB[e]) + nm1);
            }
            o.z = fmaf(v0, -inv9, 1.0f) * fmaf(n0, -inv9, 1.0f);
            o.w = fmaf(v1, -inv9, 1.0f) * fmaf(n1, -inv9, 1.0f);
        }

        // Output is write-once/never-read: non-temporal keeps it out of L2/L3.
        float* op = out + (((size_t)b * H_ + (hs + s)) * W_ + w) * C_ + cq;
        __builtin_nontemporal_store(o, reinterpret_cast<v4f*>(op));
    }
}

extern "C" void kernel_launch(void* const* d_in, const int* in_sizes, int n_in,
                              void* d_out, int out_size, void* d_ws, size_t ws_size,
                              hipStream_t stream) {
    const float* inp  = (const float*)d_in[0];
    const float* kern = (const float*)d_in[1];
    const float* mask = (const float*)d_in[2];
    float* out = (float*)d_out;

    fm_main<<<NBLK, 256, 0, stream>>>(inp, kern, mask, out);
}